// Round 11
// baseline (394.450 us; speedup 1.0000x reference)
//
#include <hip/hip_runtime.h>

// ---------------------------------------------------------------------------
// 2-layer GCN + link-prediction dot products.
// R11 = R10 + gemm1 LDS-staged rewrite. R8/R9/R10 all plateaued at ~60us:
// per-row register streaming issues 16 scattered 64B requests per wave-load
// (4x quad-redundant) with only ~8 loads/lane in flight -> MLP-starved at
// ~1.7 TB/s effective. Now: stage 32x256 x-tile in LDS via perfectly
// coalesced loads (1KB/instr unique, 8 independent/lane), compute from LDS
// (row stride 65 float4 -> conflict-free; W as float2, quad-broadcast x).
//
// hs = (x@W1) * dinv
// gs = relu(dinv*(gather(hs)+hs)+b1) * dinv
// u  = dinv*(gather(gs)+gs);  y = u@M + w2b;  c = u.w2b
// logits[e] = y[a].u[b] + c[a] + bb     (M = W2 W2^T, w2b = W2 b2, bb = b2.b2)
// ---------------------------------------------------------------------------

#define CAP   18432   // slots per 512-node bucket (mean 16384, +16 sigma)
#define CHUNK 4096    // edges per passA1 block

// gtail seed + (M, w2b, bb) precompute in one tiny launch
__global__ void seedprep_kernel(int* __restrict__ gtail, int nb1,
                                const float* __restrict__ W2, const float* __restrict__ b2,
                                float* __restrict__ mw) {
    int t = threadIdx.x;
    if (t < nb1) gtail[t] = t * CAP;
    int r = t >> 4, cc = t & 15;
    float s = 0.0f;
    for (int j = 0; j < 64; ++j) s += W2[r * 64 + j] * W2[cc * 64 + j];
    mw[t] = s;
    if (t < 16) {
        float w = 0.0f;
        for (int j = 0; j < 64; ++j) w += W2[t * 64 + j] * b2[j];
        mw[256 + t] = w;
    }
    if (t == 0) {
        float bbv = 0.0f;
        for (int j = 0; j < 64; ++j) bbv += b2[j] * b2[j];
        mw[272] = bbv;
    }
}

// one block per CHUNK of edges: LDS-staged grouped append into bucket regions
__global__ void passA1_kernel(const int* __restrict__ src, const int* __restrict__ dst, int E,
                              int* __restrict__ gtail, unsigned* __restrict__ tmp, int nb1) {
    __shared__ int cnt[256];
    __shared__ int base[256];
    int t = threadIdx.x;
    int c0 = blockIdx.x * CHUNK;
    if (t < nb1) cnt[t] = 0;
    __syncthreads();
    unsigned rec[16];   // (src | dlow<<20)
    unsigned brk[16];   // (bucket<<16 | rank)
    #pragma unroll
    for (int j = 0; j < 16; ++j) {
        int e = c0 + t + j * 256;
        if (e < E) {
            int s = src[e], d = dst[e];
            int b = d >> 9;
            int r = atomicAdd(&cnt[b], 1);
            rec[j] = (unsigned)s | ((unsigned)(d & 511) << 20);
            brk[j] = ((unsigned)b << 16) | (unsigned)r;
        }
    }
    __syncthreads();
    if (t < nb1) base[t] = atomicAdd(&gtail[t], cnt[t]);
    __syncthreads();
    #pragma unroll
    for (int j = 0; j < 16; ++j) {
        int e = c0 + t + j * 256;
        if (e < E) {
            int b = (int)(brk[j] >> 16), r = (int)(brk[j] & 0xFFFFu);
            tmp[base[b] + r] = rec[j];
        }
    }
}

// one block per coarse bucket: stream records twice; 512-entry LDS hist/scan/
// cursors -> eidx placement + rowptr/counts/dinv emission.
__global__ void fill2_kernel(const int* __restrict__ gtail, const unsigned* __restrict__ tmp,
                             int* __restrict__ eidx, int* __restrict__ rowptr,
                             int* __restrict__ counts, float* __restrict__ dinv, int n) {
    int b = blockIdx.x;
    int t = threadIdx.x;
    int beg = b * CAP;
    int cnt_total = gtail[b] - beg;
    __shared__ int h[512];
    __shared__ int cur[512];
    h[t] = 0; h[t + 256] = 0;
    __syncthreads();
    for (int i = t; i < cnt_total; i += 256) {
        unsigned r = tmp[beg + i];
        atomicAdd(&h[r >> 20], 1);
    }
    __syncthreads();
    if (t == 0) {
        int run = beg;
        for (int j = 0; j < 512; ++j) { int c = h[j]; cur[j] = run; run += c; }
    }
    __syncthreads();
    for (int j = t; j < 512; j += 256) {
        int v = (b << 9) + j;
        if (v < n) {
            rowptr[v] = cur[j];
            counts[v] = h[j];
            dinv[v]   = rsqrtf((float)h[j] + 1.0f);   // +1: self loop
        }
    }
    __syncthreads();   // rowptr reads of cur must finish before placement mutates it
    for (int i = t; i < cnt_total; i += 256) {
        unsigned r = tmp[beg + i];
        int p = atomicAdd(&cur[r >> 20], 1);
        eidx[p] = (int)(r & 0xFFFFF);
    }
}

// hs[row][:] = (x[row][:] @ W1) * dinv[row].
// LDS-staged: 32-row x-tile, coalesced staging (8 independent 1KB-unique
// loads/lane), compute 8 lanes/row (lane owns 2 cols). x rows padded to
// 65 float4 so the 8 concurrent rows hit distinct banks.
__global__ void gemm1_kernel(const float* __restrict__ x, const float* __restrict__ W1,
                             const float* __restrict__ dinv, float* __restrict__ hs, int n) {
    __shared__ float sx[32 * 260];                // 32 rows x 256 cols, stride 260 floats
    __shared__ float sw[4096];                    // W1: 256x16
    int t = threadIdx.x;
    const float4* W14 = (const float4*)W1;
    float4* sw4 = (float4*)sw;
    for (int i = t; i < 1024; i += 256) sw4[i] = W14[i];
    int rb = blockIdx.x * 32;
    const float4* xg = (const float4*)x;          // global float4 idx = rb*64 + f
    float4* sx4 = (float4*)sx;
    #pragma unroll
    for (int i = 0; i < 8; ++i) {
        int f = t + 256 * i;                      // f in [0,2048): row=f>>6, col=f&63
        int row = rb + (f >> 6);
        if (row < n) sx4[(f >> 6) * 65 + (f & 63)] = xg[(size_t)rb * 64 + f];
    }
    __syncthreads();
    int rl = t >> 3;                              // local row 0..31
    int row = rb + rl;
    if (row >= n) return;
    int l8 = t & 7;                               // lane owns cols 2*l8, 2*l8+1
    const float4* xr = &sx4[rl * 65];
    const float2* sw2 = (const float2*)sw;        // float2 idx = k*8 + l8
    float a0 = 0.0f, a1 = 0.0f;
    #pragma unroll 4
    for (int k4 = 0; k4 < 64; ++k4) {
        float4 xv = xr[k4];
        int k = k4 * 4;
        float2 w0 = sw2[(k + 0) * 8 + l8];
        float2 w1 = sw2[(k + 1) * 8 + l8];
        float2 w2 = sw2[(k + 2) * 8 + l8];
        float2 w3 = sw2[(k + 3) * 8 + l8];
        a0 += xv.x * w0.x + xv.y * w1.x + xv.z * w2.x + xv.w * w3.x;
        a1 += xv.x * w0.y + xv.y * w1.y + xv.z * w2.y + xv.w * w3.y;
    }
    float di = dinv[row];
    *(float2*)(hs + (size_t)row * 16 + 2 * l8) = make_float2(a0 * di, a1 * di);
}

// layer-1 aggregate: 8 lanes/node (2 per feature-quad), unroll-4 gathers.
__global__ void agg1_kernel(const int* __restrict__ rowptr, const int* __restrict__ counts,
                            const int* __restrict__ eidx, const float4* __restrict__ hs4,
                            const float* __restrict__ dinv, const float* __restrict__ b1,
                            float4* __restrict__ gs4, int n) {
    int t = blockIdx.x * blockDim.x + threadIdx.x;
    int v = t >> 3;
    if (v >= n) return;
    int q = t & 3, hh = (t >> 2) & 1;
    int start = rowptr[v], cnt = counts[v];
    float4 s = {0, 0, 0, 0};
    int i = hh;
    for (; i + 6 < cnt; i += 8) {
        int s0 = eidx[start + i];
        int s1 = eidx[start + i + 2];
        int s2 = eidx[start + i + 4];
        int s3 = eidx[start + i + 6];
        float4 h0 = hs4[(size_t)s0 * 4 + q];
        float4 h1 = hs4[(size_t)s1 * 4 + q];
        float4 h2 = hs4[(size_t)s2 * 4 + q];
        float4 h3 = hs4[(size_t)s3 * 4 + q];
        s.x += h0.x + h1.x + h2.x + h3.x;
        s.y += h0.y + h1.y + h2.y + h3.y;
        s.z += h0.z + h1.z + h2.z + h3.z;
        s.w += h0.w + h1.w + h2.w + h3.w;
    }
    for (; i < cnt; i += 2) {
        float4 h0 = hs4[(size_t)eidx[start + i] * 4 + q];
        s.x += h0.x; s.y += h0.y; s.z += h0.z; s.w += h0.w;
    }
    // merge the two edge-halves (lanes differing in bit 2)
    s.x += __shfl_xor(s.x, 4);
    s.y += __shfl_xor(s.y, 4);
    s.z += __shfl_xor(s.z, 4);
    s.w += __shfl_xor(s.w, 4);
    if (hh == 0) {
        float di = dinv[v];
        float4 h = hs4[(size_t)v * 4 + q];
        float4 b = ((const float4*)b1)[q];
        float4 z;
        z.x = fmaxf(di * (s.x + h.x) + b.x, 0.0f) * di;
        z.y = fmaxf(di * (s.y + h.y) + b.y, 0.0f) * di;
        z.z = fmaxf(di * (s.z + h.z) + b.z, 0.0f) * di;
        z.w = fmaxf(di * (s.w + h.w) + b.w, 0.0f) * di;
        gs4[(size_t)v * 4 + q] = z;
    }
}

// layer-2 aggregate + factorized epilogue: u = dinv*(gather(gs)+gs);
// y = u@M + w2b; c = u.w2b.  256 threads = 32 nodes x 8 lanes.
__global__ void agg2y_kernel(const int* __restrict__ rowptr, const int* __restrict__ counts,
                             const int* __restrict__ eidx, const float4* __restrict__ gs4,
                             const float* __restrict__ dinv, const float* __restrict__ mw,
                             float4* __restrict__ u4, float* __restrict__ y,
                             float* __restrict__ c, int n) {
    __shared__ float su[32 * 16];   // u for this block's 32 nodes
    __shared__ float sM[256];
    __shared__ float sw[16];
    int t = threadIdx.x;
    sM[t] = mw[t];
    if (t < 16) sw[t] = mw[256 + t];

    int j = t >> 3, q = t & 3, hh = (t >> 2) & 1;
    int v = blockIdx.x * 32 + j;
    if (v < n) {
        int start = rowptr[v], cnt = counts[v];
        float4 s = {0, 0, 0, 0};
        int i = hh;
        for (; i + 6 < cnt; i += 8) {
            int s0 = eidx[start + i];
            int s1 = eidx[start + i + 2];
            int s2 = eidx[start + i + 4];
            int s3 = eidx[start + i + 6];
            float4 g0 = gs4[(size_t)s0 * 4 + q];
            float4 g1 = gs4[(size_t)s1 * 4 + q];
            float4 g2 = gs4[(size_t)s2 * 4 + q];
            float4 g3 = gs4[(size_t)s3 * 4 + q];
            s.x += g0.x + g1.x + g2.x + g3.x;
            s.y += g0.y + g1.y + g2.y + g3.y;
            s.z += g0.z + g1.z + g2.z + g3.z;
            s.w += g0.w + g1.w + g2.w + g3.w;
        }
        for (; i < cnt; i += 2) {
            float4 g0 = gs4[(size_t)eidx[start + i] * 4 + q];
            s.x += g0.x; s.y += g0.y; s.z += g0.z; s.w += g0.w;
        }
        s.x += __shfl_xor(s.x, 4);
        s.y += __shfl_xor(s.y, 4);
        s.z += __shfl_xor(s.z, 4);
        s.w += __shfl_xor(s.w, 4);
        if (hh == 0) {
            float di = dinv[v];
            float4 g = gs4[(size_t)v * 4 + q];
            float4 uu;
            uu.x = di * (s.x + g.x);
            uu.y = di * (s.y + g.y);
            uu.z = di * (s.z + g.z);
            uu.w = di * (s.w + g.w);
            float* up = &su[j * 16 + q * 4];
            up[0] = uu.x; up[1] = uu.y; up[2] = uu.z; up[3] = uu.w;
            u4[(size_t)v * 4 + q] = uu;
        }
    }
    __syncthreads();
    if (v < n) {
        int l8 = t & 7;
        const float* uu = &su[j * 16];
        int c0 = l8 * 2;
        float y0 = sw[c0], y1 = sw[c0 + 1];
        #pragma unroll
        for (int k = 0; k < 16; ++k) {
            float uk = uu[k];
            y0 += uk * sM[k * 16 + c0];
            y1 += uk * sM[k * 16 + c0 + 1];
        }
        float2* yp = (float2*)(y + (size_t)v * 16 + c0);
        *yp = make_float2(y0, y1);
        if (l8 == 0) {
            float cv = 0.0f;
            #pragma unroll
            for (int k = 0; k < 16; ++k) cv += uu[k] * sw[k];
            c[v] = cv;
        }
    }
}

// 16 lanes per pair: one pos edge + one neg edge.
// logit = y[a].u[b] + c[a] + bb
__global__ void edge_dot_kernel(const int* __restrict__ pa, const int* __restrict__ pb,
                                const int* __restrict__ na, const int* __restrict__ nb_,
                                int ET, const float* __restrict__ u, const float* __restrict__ y,
                                const float* __restrict__ c, const float* __restrict__ mw,
                                float* __restrict__ out) {
    int t = blockIdx.x * blockDim.x + threadIdx.x;
    int p = t >> 4, l = t & 15;
    if (p >= ET) return;
    int a0 = pa[p], b0 = pb[p];
    int a1 = na[p], b1 = nb_[p];
    float ya0 = y[(size_t)a0 * 16 + l];
    float ub0 = u[(size_t)b0 * 16 + l];
    float ya1 = y[(size_t)a1 * 16 + l];
    float ub1 = u[(size_t)b1 * 16 + l];
    float p0 = ya0 * ub0;
    float p1 = ya1 * ub1;
    p0 += __shfl_xor(p0, 1);  p1 += __shfl_xor(p1, 1);
    p0 += __shfl_xor(p0, 2);  p1 += __shfl_xor(p1, 2);
    p0 += __shfl_xor(p0, 4);  p1 += __shfl_xor(p1, 4);
    p0 += __shfl_xor(p0, 8);  p1 += __shfl_xor(p1, 8);
    if (l == 0) {
        float bb = mw[272];
        out[p]      = p0 + c[a0] + bb;
        out[ET + p] = p1 + c[a1] + bb;
    }
}

extern "C" void kernel_launch(void* const* d_in, const int* in_sizes, int n_in,
                              void* d_out, int out_size, void* d_ws, size_t ws_size,
                              hipStream_t stream) {
    const float* x    = (const float*)d_in[0];
    const int*   tei  = (const int*)d_in[1];
    const int*   tpos = (const int*)d_in[2];
    const int*   tneg = (const int*)d_in[3];
    const float* W1   = (const float*)d_in[4];
    const float* b1   = (const float*)d_in[5];
    const float* W2   = (const float*)d_in[6];
    const float* b2   = (const float*)d_in[7];
    float* out = (float*)d_out;

    int n   = in_sizes[0] / 256;    // 100000 nodes
    int E   = in_sizes[1] / 2;      // 3.2M train edges
    int ET  = in_sizes[2] / 2;      // 500K test edges each
    int nb1 = (n + 511) >> 9;       // 196 coarse buckets

    // workspace layout (no aliasing)
    char* w = (char*)d_ws;
    int*   gtail  = (int*)w;        w += 256 * 4;
    float* mw     = (float*)w;      w += 512 * 4;
    int*   rowptr = (int*)w;        w += (size_t)n * 4;
    int*   counts = (int*)w;        w += (size_t)n * 4;
    float* dinv   = (float*)w;      w += (size_t)n * 4;
    float* hs     = (float*)w;      w += (size_t)16 * n * 4;
    float* gs     = (float*)w;      w += (size_t)16 * n * 4;
    float* u      = (float*)w;      w += (size_t)16 * n * 4;
    float* y      = (float*)w;      w += (size_t)16 * n * 4;
    float* c      = (float*)w;      w += (size_t)n * 4;
    int*   eidx   = (int*)w;        w += (size_t)nb1 * CAP * 4;
    unsigned* tmp = (unsigned*)w;   w += (size_t)nb1 * CAP * 4;

    const int* src = tei;
    const int* dst = tei + E;

    seedprep_kernel<<<1, 256, 0, stream>>>(gtail, nb1, W2, b2, mw);
    passA1_kernel<<<(E + CHUNK - 1) / CHUNK, 256, 0, stream>>>(src, dst, E, gtail, tmp, nb1);
    fill2_kernel<<<nb1, 256, 0, stream>>>(gtail, tmp, eidx, rowptr, counts, dinv, n);

    gemm1_kernel<<<(n + 31) / 32, 256, 0, stream>>>(x, W1, dinv, hs, n);
    agg1_kernel<<<(8 * n + 255) / 256, 256, 0, stream>>>(rowptr, counts, eidx,
                                                         (const float4*)hs, dinv, b1,
                                                         (float4*)gs, n);
    agg2y_kernel<<<(n + 31) / 32, 256, 0, stream>>>(rowptr, counts, eidx,
                                                    (const float4*)gs, dinv, mw,
                                                    (float4*)u, y, c, n);
    edge_dot_kernel<<<(16 * ET + 255) / 256, 256, 0, stream>>>(tpos, tpos + ET, tneg, tneg + ET,
                                                               ET, u, y, c, mw, out);
}

// Round 12
// 390.765 us; speedup vs baseline: 1.0094x; 1.0094x over previous
//
#include <hip/hip_runtime.h>

// ---------------------------------------------------------------------------
// 2-layer GCN + link-prediction dot products.
// R12 = R11 + gemm1 de-LDS'd. R8-R11 all plateaued ~60us; R11 counters showed
// VALUBusy 15%, conflicts 0, HBM 930 GB/s -> the common limiter was the
// per-CU LDS pipe (~12cyc/ds_read_b128; 256-320 LDS instr/thread). Now W1 is
// read directly from global with wave-uniform indices -> compiler emits
// s_load (scalar cache, SMEM pipe); x streamed per-row as float4. No LDS.
//
// hs = (x@W1) * dinv
// gs = relu(dinv*(gather(hs)+hs)+b1) * dinv
// u  = dinv*(gather(gs)+gs);  y = u@M + w2b;  c = u.w2b
// logits[e] = y[a].u[b] + c[a] + bb     (M = W2 W2^T, w2b = W2 b2, bb = b2.b2)
// ---------------------------------------------------------------------------

#define CAP   18432   // slots per 512-node bucket (mean 16384, +16 sigma)
#define CHUNK 4096    // edges per passA1 block

// gtail seed + (M, w2b, bb) precompute in one tiny launch
__global__ void seedprep_kernel(int* __restrict__ gtail, int nb1,
                                const float* __restrict__ W2, const float* __restrict__ b2,
                                float* __restrict__ mw) {
    int t = threadIdx.x;
    if (t < nb1) gtail[t] = t * CAP;
    int r = t >> 4, cc = t & 15;
    float s = 0.0f;
    for (int j = 0; j < 64; ++j) s += W2[r * 64 + j] * W2[cc * 64 + j];
    mw[t] = s;
    if (t < 16) {
        float w = 0.0f;
        for (int j = 0; j < 64; ++j) w += W2[t * 64 + j] * b2[j];
        mw[256 + t] = w;
    }
    if (t == 0) {
        float bbv = 0.0f;
        for (int j = 0; j < 64; ++j) bbv += b2[j] * b2[j];
        mw[272] = bbv;
    }
}

// one block per CHUNK of edges: LDS-staged grouped append into bucket regions
__global__ void passA1_kernel(const int* __restrict__ src, const int* __restrict__ dst, int E,
                              int* __restrict__ gtail, unsigned* __restrict__ tmp, int nb1) {
    __shared__ int cnt[256];
    __shared__ int base[256];
    int t = threadIdx.x;
    int c0 = blockIdx.x * CHUNK;
    if (t < nb1) cnt[t] = 0;
    __syncthreads();
    unsigned rec[16];   // (src | dlow<<20)
    unsigned brk[16];   // (bucket<<16 | rank)
    #pragma unroll
    for (int j = 0; j < 16; ++j) {
        int e = c0 + t + j * 256;
        if (e < E) {
            int s = src[e], d = dst[e];
            int b = d >> 9;
            int r = atomicAdd(&cnt[b], 1);
            rec[j] = (unsigned)s | ((unsigned)(d & 511) << 20);
            brk[j] = ((unsigned)b << 16) | (unsigned)r;
        }
    }
    __syncthreads();
    if (t < nb1) base[t] = atomicAdd(&gtail[t], cnt[t]);
    __syncthreads();
    #pragma unroll
    for (int j = 0; j < 16; ++j) {
        int e = c0 + t + j * 256;
        if (e < E) {
            int b = (int)(brk[j] >> 16), r = (int)(brk[j] & 0xFFFFu);
            tmp[base[b] + r] = rec[j];
        }
    }
}

// one block per coarse bucket: stream records twice; 512-entry LDS hist/scan/
// cursors -> eidx placement + rowptr/counts/dinv emission.
__global__ void fill2_kernel(const int* __restrict__ gtail, const unsigned* __restrict__ tmp,
                             int* __restrict__ eidx, int* __restrict__ rowptr,
                             int* __restrict__ counts, float* __restrict__ dinv, int n) {
    int b = blockIdx.x;
    int t = threadIdx.x;
    int beg = b * CAP;
    int cnt_total = gtail[b] - beg;
    __shared__ int h[512];
    __shared__ int cur[512];
    h[t] = 0; h[t + 256] = 0;
    __syncthreads();
    for (int i = t; i < cnt_total; i += 256) {
        unsigned r = tmp[beg + i];
        atomicAdd(&h[r >> 20], 1);
    }
    __syncthreads();
    if (t == 0) {
        int run = beg;
        for (int j = 0; j < 512; ++j) { int c = h[j]; cur[j] = run; run += c; }
    }
    __syncthreads();
    for (int j = t; j < 512; j += 256) {
        int v = (b << 9) + j;
        if (v < n) {
            rowptr[v] = cur[j];
            counts[v] = h[j];
            dinv[v]   = rsqrtf((float)h[j] + 1.0f);   // +1: self loop
        }
    }
    __syncthreads();   // rowptr reads of cur must finish before placement mutates it
    for (int i = t; i < cnt_total; i += 256) {
        unsigned r = tmp[beg + i];
        int p = atomicAdd(&cur[r >> 20], 1);
        eidx[p] = (int)(r & 0xFFFFF);
    }
}

// hs[row][:] = (x[row][:] @ W1) * dinv[row].  1 row/thread; x streamed as
// float4 from global; W1 read with wave-uniform indices -> scalar loads
// (SMEM pipe, scalar-cache resident 16 KB). No LDS at all.
__global__ void gemm1_kernel(const float* __restrict__ x, const float* __restrict__ W1,
                             const float* __restrict__ dinv, float* __restrict__ hs, int n) {
    int row = blockIdx.x * 256 + threadIdx.x;
    if (row >= n) return;
    const float4* x4 = (const float4*)(x + (size_t)row * 256);
    const float4* W14 = (const float4*)W1;   // uniform-indexed -> s_load
    float4 a0 = {0,0,0,0}, a1 = {0,0,0,0}, a2 = {0,0,0,0}, a3 = {0,0,0,0};
    for (int k4 = 0; k4 < 64; ++k4) {
        float4 xv = x4[k4];
        #pragma unroll
        for (int j = 0; j < 4; ++j) {
            float xk = (j == 0) ? xv.x : (j == 1) ? xv.y : (j == 2) ? xv.z : xv.w;
            int k = (k4 << 2) + j;
            float4 w0 = W14[k * 4 + 0];
            float4 w1 = W14[k * 4 + 1];
            float4 w2 = W14[k * 4 + 2];
            float4 w3 = W14[k * 4 + 3];
            a0.x += xk * w0.x; a0.y += xk * w0.y; a0.z += xk * w0.z; a0.w += xk * w0.w;
            a1.x += xk * w1.x; a1.y += xk * w1.y; a1.z += xk * w1.z; a1.w += xk * w1.w;
            a2.x += xk * w2.x; a2.y += xk * w2.y; a2.z += xk * w2.z; a2.w += xk * w2.w;
            a3.x += xk * w3.x; a3.y += xk * w3.y; a3.z += xk * w3.z; a3.w += xk * w3.w;
        }
    }
    float di = dinv[row];
    float4* o = (float4*)(hs + (size_t)row * 16);
    a0.x *= di; a0.y *= di; a0.z *= di; a0.w *= di;
    a1.x *= di; a1.y *= di; a1.z *= di; a1.w *= di;
    a2.x *= di; a2.y *= di; a2.z *= di; a2.w *= di;
    a3.x *= di; a3.y *= di; a3.z *= di; a3.w *= di;
    o[0] = a0; o[1] = a1; o[2] = a2; o[3] = a3;
}

// layer-1 aggregate: 8 lanes/node (2 per feature-quad), unroll-4 gathers.
__global__ void agg1_kernel(const int* __restrict__ rowptr, const int* __restrict__ counts,
                            const int* __restrict__ eidx, const float4* __restrict__ hs4,
                            const float* __restrict__ dinv, const float* __restrict__ b1,
                            float4* __restrict__ gs4, int n) {
    int t = blockIdx.x * blockDim.x + threadIdx.x;
    int v = t >> 3;
    if (v >= n) return;
    int q = t & 3, hh = (t >> 2) & 1;
    int start = rowptr[v], cnt = counts[v];
    float4 s = {0, 0, 0, 0};
    int i = hh;
    for (; i + 6 < cnt; i += 8) {
        int s0 = eidx[start + i];
        int s1 = eidx[start + i + 2];
        int s2 = eidx[start + i + 4];
        int s3 = eidx[start + i + 6];
        float4 h0 = hs4[(size_t)s0 * 4 + q];
        float4 h1 = hs4[(size_t)s1 * 4 + q];
        float4 h2 = hs4[(size_t)s2 * 4 + q];
        float4 h3 = hs4[(size_t)s3 * 4 + q];
        s.x += h0.x + h1.x + h2.x + h3.x;
        s.y += h0.y + h1.y + h2.y + h3.y;
        s.z += h0.z + h1.z + h2.z + h3.z;
        s.w += h0.w + h1.w + h2.w + h3.w;
    }
    for (; i < cnt; i += 2) {
        float4 h0 = hs4[(size_t)eidx[start + i] * 4 + q];
        s.x += h0.x; s.y += h0.y; s.z += h0.z; s.w += h0.w;
    }
    // merge the two edge-halves (lanes differing in bit 2)
    s.x += __shfl_xor(s.x, 4);
    s.y += __shfl_xor(s.y, 4);
    s.z += __shfl_xor(s.z, 4);
    s.w += __shfl_xor(s.w, 4);
    if (hh == 0) {
        float di = dinv[v];
        float4 h = hs4[(size_t)v * 4 + q];
        float4 b = ((const float4*)b1)[q];
        float4 z;
        z.x = fmaxf(di * (s.x + h.x) + b.x, 0.0f) * di;
        z.y = fmaxf(di * (s.y + h.y) + b.y, 0.0f) * di;
        z.z = fmaxf(di * (s.z + h.z) + b.z, 0.0f) * di;
        z.w = fmaxf(di * (s.w + h.w) + b.w, 0.0f) * di;
        gs4[(size_t)v * 4 + q] = z;
    }
}

// layer-2 aggregate + factorized epilogue: u = dinv*(gather(gs)+gs);
// y = u@M + w2b; c = u.w2b.  256 threads = 32 nodes x 8 lanes.
__global__ void agg2y_kernel(const int* __restrict__ rowptr, const int* __restrict__ counts,
                             const int* __restrict__ eidx, const float4* __restrict__ gs4,
                             const float* __restrict__ dinv, const float* __restrict__ mw,
                             float4* __restrict__ u4, float* __restrict__ y,
                             float* __restrict__ c, int n) {
    __shared__ float su[32 * 16];   // u for this block's 32 nodes
    __shared__ float sM[256];
    __shared__ float sw[16];
    int t = threadIdx.x;
    sM[t] = mw[t];
    if (t < 16) sw[t] = mw[256 + t];

    int j = t >> 3, q = t & 3, hh = (t >> 2) & 1;
    int v = blockIdx.x * 32 + j;
    if (v < n) {
        int start = rowptr[v], cnt = counts[v];
        float4 s = {0, 0, 0, 0};
        int i = hh;
        for (; i + 6 < cnt; i += 8) {
            int s0 = eidx[start + i];
            int s1 = eidx[start + i + 2];
            int s2 = eidx[start + i + 4];
            int s3 = eidx[start + i + 6];
            float4 g0 = gs4[(size_t)s0 * 4 + q];
            float4 g1 = gs4[(size_t)s1 * 4 + q];
            float4 g2 = gs4[(size_t)s2 * 4 + q];
            float4 g3 = gs4[(size_t)s3 * 4 + q];
            s.x += g0.x + g1.x + g2.x + g3.x;
            s.y += g0.y + g1.y + g2.y + g3.y;
            s.z += g0.z + g1.z + g2.z + g3.z;
            s.w += g0.w + g1.w + g2.w + g3.w;
        }
        for (; i < cnt; i += 2) {
            float4 g0 = gs4[(size_t)eidx[start + i] * 4 + q];
            s.x += g0.x; s.y += g0.y; s.z += g0.z; s.w += g0.w;
        }
        s.x += __shfl_xor(s.x, 4);
        s.y += __shfl_xor(s.y, 4);
        s.z += __shfl_xor(s.z, 4);
        s.w += __shfl_xor(s.w, 4);
        if (hh == 0) {
            float di = dinv[v];
            float4 g = gs4[(size_t)v * 4 + q];
            float4 uu;
            uu.x = di * (s.x + g.x);
            uu.y = di * (s.y + g.y);
            uu.z = di * (s.z + g.z);
            uu.w = di * (s.w + g.w);
            float* up = &su[j * 16 + q * 4];
            up[0] = uu.x; up[1] = uu.y; up[2] = uu.z; up[3] = uu.w;
            u4[(size_t)v * 4 + q] = uu;
        }
    }
    __syncthreads();
    if (v < n) {
        int l8 = t & 7;
        const float* uu = &su[j * 16];
        int c0 = l8 * 2;
        float y0 = sw[c0], y1 = sw[c0 + 1];
        #pragma unroll
        for (int k = 0; k < 16; ++k) {
            float uk = uu[k];
            y0 += uk * sM[k * 16 + c0];
            y1 += uk * sM[k * 16 + c0 + 1];
        }
        float2* yp = (float2*)(y + (size_t)v * 16 + c0);
        *yp = make_float2(y0, y1);
        if (l8 == 0) {
            float cv = 0.0f;
            #pragma unroll
            for (int k = 0; k < 16; ++k) cv += uu[k] * sw[k];
            c[v] = cv;
        }
    }
}

// 16 lanes per pair: one pos edge + one neg edge.
// logit = y[a].u[b] + c[a] + bb
__global__ void edge_dot_kernel(const int* __restrict__ pa, const int* __restrict__ pb,
                                const int* __restrict__ na, const int* __restrict__ nb_,
                                int ET, const float* __restrict__ u, const float* __restrict__ y,
                                const float* __restrict__ c, const float* __restrict__ mw,
                                float* __restrict__ out) {
    int t = blockIdx.x * blockDim.x + threadIdx.x;
    int p = t >> 4, l = t & 15;
    if (p >= ET) return;
    int a0 = pa[p], b0 = pb[p];
    int a1 = na[p], b1 = nb_[p];
    float ya0 = y[(size_t)a0 * 16 + l];
    float ub0 = u[(size_t)b0 * 16 + l];
    float ya1 = y[(size_t)a1 * 16 + l];
    float ub1 = u[(size_t)b1 * 16 + l];
    float p0 = ya0 * ub0;
    float p1 = ya1 * ub1;
    p0 += __shfl_xor(p0, 1);  p1 += __shfl_xor(p1, 1);
    p0 += __shfl_xor(p0, 2);  p1 += __shfl_xor(p1, 2);
    p0 += __shfl_xor(p0, 4);  p1 += __shfl_xor(p1, 4);
    p0 += __shfl_xor(p0, 8);  p1 += __shfl_xor(p1, 8);
    if (l == 0) {
        float bb = mw[272];
        out[p]      = p0 + c[a0] + bb;
        out[ET + p] = p1 + c[a1] + bb;
    }
}

extern "C" void kernel_launch(void* const* d_in, const int* in_sizes, int n_in,
                              void* d_out, int out_size, void* d_ws, size_t ws_size,
                              hipStream_t stream) {
    const float* x    = (const float*)d_in[0];
    const int*   tei  = (const int*)d_in[1];
    const int*   tpos = (const int*)d_in[2];
    const int*   tneg = (const int*)d_in[3];
    const float* W1   = (const float*)d_in[4];
    const float* b1   = (const float*)d_in[5];
    const float* W2   = (const float*)d_in[6];
    const float* b2   = (const float*)d_in[7];
    float* out = (float*)d_out;

    int n   = in_sizes[0] / 256;    // 100000 nodes
    int E   = in_sizes[1] / 2;      // 3.2M train edges
    int ET  = in_sizes[2] / 2;      // 500K test edges each
    int nb1 = (n + 511) >> 9;       // 196 coarse buckets

    // workspace layout (no aliasing)
    char* w = (char*)d_ws;
    int*   gtail  = (int*)w;        w += 256 * 4;
    float* mw     = (float*)w;      w += 512 * 4;
    int*   rowptr = (int*)w;        w += (size_t)n * 4;
    int*   counts = (int*)w;        w += (size_t)n * 4;
    float* dinv   = (float*)w;      w += (size_t)n * 4;
    float* hs     = (float*)w;      w += (size_t)16 * n * 4;
    float* gs     = (float*)w;      w += (size_t)16 * n * 4;
    float* u      = (float*)w;      w += (size_t)16 * n * 4;
    float* y      = (float*)w;      w += (size_t)16 * n * 4;
    float* c      = (float*)w;      w += (size_t)n * 4;
    int*   eidx   = (int*)w;        w += (size_t)nb1 * CAP * 4;
    unsigned* tmp = (unsigned*)w;   w += (size_t)nb1 * CAP * 4;

    const int* src = tei;
    const int* dst = tei + E;

    seedprep_kernel<<<1, 256, 0, stream>>>(gtail, nb1, W2, b2, mw);
    passA1_kernel<<<(E + CHUNK - 1) / CHUNK, 256, 0, stream>>>(src, dst, E, gtail, tmp, nb1);
    fill2_kernel<<<nb1, 256, 0, stream>>>(gtail, tmp, eidx, rowptr, counts, dinv, n);

    gemm1_kernel<<<(n + 255) / 256, 256, 0, stream>>>(x, W1, dinv, hs, n);
    agg1_kernel<<<(8 * n + 255) / 256, 256, 0, stream>>>(rowptr, counts, eidx,
                                                         (const float4*)hs, dinv, b1,
                                                         (float4*)gs, n);
    agg2y_kernel<<<(n + 31) / 32, 256, 0, stream>>>(rowptr, counts, eidx,
                                                    (const float4*)gs, dinv, mw,
                                                    (float4*)u, y, c, n);
    edge_dot_kernel<<<(16 * ET + 255) / 256, 256, 0, stream>>>(tpos, tpos + ET, tneg, tneg + ET,
                                                               ET, u, y, c, mw, out);
}

// Round 13
// 384.208 us; speedup vs baseline: 1.0267x; 1.0171x over previous
//
#include <hip/hip_runtime.h>

// ---------------------------------------------------------------------------
// 2-layer GCN + link-prediction dot products.
// R13 = R12 + gemm1 MLP fix. R12 disclosed VGPR_Count=16: compiler kept only
// the 16 accumulators in VGPRs -> 1 x-load in flight -> ~1 TB/s latency-bound
// (matches 5 structures all stuck at ~60us for different pipe reasons).
// Now: W1 stays in SGPRs (uniform s_load, scalar cache), x prefetched 8-deep
// into an explicit float4 buf[8] (8 independent VMEM loads in flight), and
// 64-thread single-wave blocks (1563 blocks) for CU load balance.
//
// hs = (x@W1) * dinv
// gs = relu(dinv*(gather(hs)+hs)+b1) * dinv
// u  = dinv*(gather(gs)+gs);  y = u@M + w2b;  c = u.w2b
// logits[e] = y[a].u[b] + c[a] + bb     (M = W2 W2^T, w2b = W2 b2, bb = b2.b2)
// ---------------------------------------------------------------------------

#define CAP   18432   // slots per 512-node bucket (mean 16384, +16 sigma)
#define CHUNK 4096    // edges per passA1 block

// gtail seed + (M, w2b, bb) precompute in one tiny launch
__global__ void seedprep_kernel(int* __restrict__ gtail, int nb1,
                                const float* __restrict__ W2, const float* __restrict__ b2,
                                float* __restrict__ mw) {
    int t = threadIdx.x;
    if (t < nb1) gtail[t] = t * CAP;
    int r = t >> 4, cc = t & 15;
    float s = 0.0f;
    for (int j = 0; j < 64; ++j) s += W2[r * 64 + j] * W2[cc * 64 + j];
    mw[t] = s;
    if (t < 16) {
        float w = 0.0f;
        for (int j = 0; j < 64; ++j) w += W2[t * 64 + j] * b2[j];
        mw[256 + t] = w;
    }
    if (t == 0) {
        float bbv = 0.0f;
        for (int j = 0; j < 64; ++j) bbv += b2[j] * b2[j];
        mw[272] = bbv;
    }
}

// one block per CHUNK of edges: LDS-staged grouped append into bucket regions
__global__ void passA1_kernel(const int* __restrict__ src, const int* __restrict__ dst, int E,
                              int* __restrict__ gtail, unsigned* __restrict__ tmp, int nb1) {
    __shared__ int cnt[256];
    __shared__ int base[256];
    int t = threadIdx.x;
    int c0 = blockIdx.x * CHUNK;
    if (t < nb1) cnt[t] = 0;
    __syncthreads();
    unsigned rec[16];   // (src | dlow<<20)
    unsigned brk[16];   // (bucket<<16 | rank)
    #pragma unroll
    for (int j = 0; j < 16; ++j) {
        int e = c0 + t + j * 256;
        if (e < E) {
            int s = src[e], d = dst[e];
            int b = d >> 9;
            int r = atomicAdd(&cnt[b], 1);
            rec[j] = (unsigned)s | ((unsigned)(d & 511) << 20);
            brk[j] = ((unsigned)b << 16) | (unsigned)r;
        }
    }
    __syncthreads();
    if (t < nb1) base[t] = atomicAdd(&gtail[t], cnt[t]);
    __syncthreads();
    #pragma unroll
    for (int j = 0; j < 16; ++j) {
        int e = c0 + t + j * 256;
        if (e < E) {
            int b = (int)(brk[j] >> 16), r = (int)(brk[j] & 0xFFFFu);
            tmp[base[b] + r] = rec[j];
        }
    }
}

// one block per coarse bucket: stream records twice; 512-entry LDS hist/scan/
// cursors -> eidx placement + rowptr/counts/dinv emission.
__global__ void fill2_kernel(const int* __restrict__ gtail, const unsigned* __restrict__ tmp,
                             int* __restrict__ eidx, int* __restrict__ rowptr,
                             int* __restrict__ counts, float* __restrict__ dinv, int n) {
    int b = blockIdx.x;
    int t = threadIdx.x;
    int beg = b * CAP;
    int cnt_total = gtail[b] - beg;
    __shared__ int h[512];
    __shared__ int cur[512];
    h[t] = 0; h[t + 256] = 0;
    __syncthreads();
    for (int i = t; i < cnt_total; i += 256) {
        unsigned r = tmp[beg + i];
        atomicAdd(&h[r >> 20], 1);
    }
    __syncthreads();
    if (t == 0) {
        int run = beg;
        for (int j = 0; j < 512; ++j) { int c = h[j]; cur[j] = run; run += c; }
    }
    __syncthreads();
    for (int j = t; j < 512; j += 256) {
        int v = (b << 9) + j;
        if (v < n) {
            rowptr[v] = cur[j];
            counts[v] = h[j];
            dinv[v]   = rsqrtf((float)h[j] + 1.0f);   // +1: self loop
        }
    }
    __syncthreads();   // rowptr reads of cur must finish before placement mutates it
    for (int i = t; i < cnt_total; i += 256) {
        unsigned r = tmp[beg + i];
        int p = atomicAdd(&cur[r >> 20], 1);
        eidx[p] = (int)(r & 0xFFFFF);
    }
}

// hs[row][:] = (x[row][:] @ W1) * dinv[row].  1 row/thread, 64-thread
// single-wave blocks; W1 via wave-uniform s_load (scalar cache); x prefetched
// 8-deep into registers for memory-level parallelism.
__global__ void __launch_bounds__(64)
gemm1_kernel(const float* __restrict__ x, const float* __restrict__ W1,
             const float* __restrict__ dinv, float* __restrict__ hs, int n) {
    int row = blockIdx.x * 64 + threadIdx.x;
    if (row >= n) return;
    const float4* x4 = (const float4*)(x + (size_t)row * 256);
    const float4* W14 = (const float4*)W1;   // uniform-indexed -> s_load
    float4 a0 = {0,0,0,0}, a1 = {0,0,0,0}, a2 = {0,0,0,0}, a3 = {0,0,0,0};
    float4 buf[8];
    #pragma unroll
    for (int j = 0; j < 8; ++j) buf[j] = x4[j];
    for (int k8 = 0; k8 < 8; ++k8) {
        float4 cur[8];
        #pragma unroll
        for (int j = 0; j < 8; ++j) cur[j] = buf[j];
        if (k8 < 7) {
            #pragma unroll
            for (int j = 0; j < 8; ++j) buf[j] = x4[(k8 + 1) * 8 + j];
        }
        #pragma unroll
        for (int jj = 0; jj < 8; ++jj) {
            float4 xv = cur[jj];
            int k4 = k8 * 8 + jj;
            #pragma unroll
            for (int j = 0; j < 4; ++j) {
                float xk = (j == 0) ? xv.x : (j == 1) ? xv.y : (j == 2) ? xv.z : xv.w;
                int k = (k4 << 2) + j;
                float4 w0 = W14[k * 4 + 0];
                float4 w1 = W14[k * 4 + 1];
                float4 w2 = W14[k * 4 + 2];
                float4 w3 = W14[k * 4 + 3];
                a0.x += xk * w0.x; a0.y += xk * w0.y; a0.z += xk * w0.z; a0.w += xk * w0.w;
                a1.x += xk * w1.x; a1.y += xk * w1.y; a1.z += xk * w1.z; a1.w += xk * w1.w;
                a2.x += xk * w2.x; a2.y += xk * w2.y; a2.z += xk * w2.z; a2.w += xk * w2.w;
                a3.x += xk * w3.x; a3.y += xk * w3.y; a3.z += xk * w3.z; a3.w += xk * w3.w;
            }
        }
    }
    float di = dinv[row];
    float4* o = (float4*)(hs + (size_t)row * 16);
    a0.x *= di; a0.y *= di; a0.z *= di; a0.w *= di;
    a1.x *= di; a1.y *= di; a1.z *= di; a1.w *= di;
    a2.x *= di; a2.y *= di; a2.z *= di; a2.w *= di;
    a3.x *= di; a3.y *= di; a3.z *= di; a3.w *= di;
    o[0] = a0; o[1] = a1; o[2] = a2; o[3] = a3;
}

// layer-1 aggregate: 8 lanes/node (2 per feature-quad), unroll-4 gathers.
__global__ void agg1_kernel(const int* __restrict__ rowptr, const int* __restrict__ counts,
                            const int* __restrict__ eidx, const float4* __restrict__ hs4,
                            const float* __restrict__ dinv, const float* __restrict__ b1,
                            float4* __restrict__ gs4, int n) {
    int t = blockIdx.x * blockDim.x + threadIdx.x;
    int v = t >> 3;
    if (v >= n) return;
    int q = t & 3, hh = (t >> 2) & 1;
    int start = rowptr[v], cnt = counts[v];
    float4 s = {0, 0, 0, 0};
    int i = hh;
    for (; i + 6 < cnt; i += 8) {
        int s0 = eidx[start + i];
        int s1 = eidx[start + i + 2];
        int s2 = eidx[start + i + 4];
        int s3 = eidx[start + i + 6];
        float4 h0 = hs4[(size_t)s0 * 4 + q];
        float4 h1 = hs4[(size_t)s1 * 4 + q];
        float4 h2 = hs4[(size_t)s2 * 4 + q];
        float4 h3 = hs4[(size_t)s3 * 4 + q];
        s.x += h0.x + h1.x + h2.x + h3.x;
        s.y += h0.y + h1.y + h2.y + h3.y;
        s.z += h0.z + h1.z + h2.z + h3.z;
        s.w += h0.w + h1.w + h2.w + h3.w;
    }
    for (; i < cnt; i += 2) {
        float4 h0 = hs4[(size_t)eidx[start + i] * 4 + q];
        s.x += h0.x; s.y += h0.y; s.z += h0.z; s.w += h0.w;
    }
    // merge the two edge-halves (lanes differing in bit 2)
    s.x += __shfl_xor(s.x, 4);
    s.y += __shfl_xor(s.y, 4);
    s.z += __shfl_xor(s.z, 4);
    s.w += __shfl_xor(s.w, 4);
    if (hh == 0) {
        float di = dinv[v];
        float4 h = hs4[(size_t)v * 4 + q];
        float4 b = ((const float4*)b1)[q];
        float4 z;
        z.x = fmaxf(di * (s.x + h.x) + b.x, 0.0f) * di;
        z.y = fmaxf(di * (s.y + h.y) + b.y, 0.0f) * di;
        z.z = fmaxf(di * (s.z + h.z) + b.z, 0.0f) * di;
        z.w = fmaxf(di * (s.w + h.w) + b.w, 0.0f) * di;
        gs4[(size_t)v * 4 + q] = z;
    }
}

// layer-2 aggregate + factorized epilogue: u = dinv*(gather(gs)+gs);
// y = u@M + w2b; c = u.w2b.  256 threads = 32 nodes x 8 lanes.
__global__ void agg2y_kernel(const int* __restrict__ rowptr, const int* __restrict__ counts,
                             const int* __restrict__ eidx, const float4* __restrict__ gs4,
                             const float* __restrict__ dinv, const float* __restrict__ mw,
                             float4* __restrict__ u4, float* __restrict__ y,
                             float* __restrict__ c, int n) {
    __shared__ float su[32 * 16];   // u for this block's 32 nodes
    __shared__ float sM[256];
    __shared__ float sw[16];
    int t = threadIdx.x;
    sM[t] = mw[t];
    if (t < 16) sw[t] = mw[256 + t];

    int j = t >> 3, q = t & 3, hh = (t >> 2) & 1;
    int v = blockIdx.x * 32 + j;
    if (v < n) {
        int start = rowptr[v], cnt = counts[v];
        float4 s = {0, 0, 0, 0};
        int i = hh;
        for (; i + 6 < cnt; i += 8) {
            int s0 = eidx[start + i];
            int s1 = eidx[start + i + 2];
            int s2 = eidx[start + i + 4];
            int s3 = eidx[start + i + 6];
            float4 g0 = gs4[(size_t)s0 * 4 + q];
            float4 g1 = gs4[(size_t)s1 * 4 + q];
            float4 g2 = gs4[(size_t)s2 * 4 + q];
            float4 g3 = gs4[(size_t)s3 * 4 + q];
            s.x += g0.x + g1.x + g2.x + g3.x;
            s.y += g0.y + g1.y + g2.y + g3.y;
            s.z += g0.z + g1.z + g2.z + g3.z;
            s.w += g0.w + g1.w + g2.w + g3.w;
        }
        for (; i < cnt; i += 2) {
            float4 g0 = gs4[(size_t)eidx[start + i] * 4 + q];
            s.x += g0.x; s.y += g0.y; s.z += g0.z; s.w += g0.w;
        }
        s.x += __shfl_xor(s.x, 4);
        s.y += __shfl_xor(s.y, 4);
        s.z += __shfl_xor(s.z, 4);
        s.w += __shfl_xor(s.w, 4);
        if (hh == 0) {
            float di = dinv[v];
            float4 g = gs4[(size_t)v * 4 + q];
            float4 uu;
            uu.x = di * (s.x + g.x);
            uu.y = di * (s.y + g.y);
            uu.z = di * (s.z + g.z);
            uu.w = di * (s.w + g.w);
            float* up = &su[j * 16 + q * 4];
            up[0] = uu.x; up[1] = uu.y; up[2] = uu.z; up[3] = uu.w;
            u4[(size_t)v * 4 + q] = uu;
        }
    }
    __syncthreads();
    if (v < n) {
        int l8 = t & 7;
        const float* uu = &su[j * 16];
        int c0 = l8 * 2;
        float y0 = sw[c0], y1 = sw[c0 + 1];
        #pragma unroll
        for (int k = 0; k < 16; ++k) {
            float uk = uu[k];
            y0 += uk * sM[k * 16 + c0];
            y1 += uk * sM[k * 16 + c0 + 1];
        }
        float2* yp = (float2*)(y + (size_t)v * 16 + c0);
        *yp = make_float2(y0, y1);
        if (l8 == 0) {
            float cv = 0.0f;
            #pragma unroll
            for (int k = 0; k < 16; ++k) cv += uu[k] * sw[k];
            c[v] = cv;
        }
    }
}

// 16 lanes per pair: one pos edge + one neg edge.
// logit = y[a].u[b] + c[a] + bb
__global__ void edge_dot_kernel(const int* __restrict__ pa, const int* __restrict__ pb,
                                const int* __restrict__ na, const int* __restrict__ nb_,
                                int ET, const float* __restrict__ u, const float* __restrict__ y,
                                const float* __restrict__ c, const float* __restrict__ mw,
                                float* __restrict__ out) {
    int t = blockIdx.x * blockDim.x + threadIdx.x;
    int p = t >> 4, l = t & 15;
    if (p >= ET) return;
    int a0 = pa[p], b0 = pb[p];
    int a1 = na[p], b1 = nb_[p];
    float ya0 = y[(size_t)a0 * 16 + l];
    float ub0 = u[(size_t)b0 * 16 + l];
    float ya1 = y[(size_t)a1 * 16 + l];
    float ub1 = u[(size_t)b1 * 16 + l];
    float p0 = ya0 * ub0;
    float p1 = ya1 * ub1;
    p0 += __shfl_xor(p0, 1);  p1 += __shfl_xor(p1, 1);
    p0 += __shfl_xor(p0, 2);  p1 += __shfl_xor(p1, 2);
    p0 += __shfl_xor(p0, 4);  p1 += __shfl_xor(p1, 4);
    p0 += __shfl_xor(p0, 8);  p1 += __shfl_xor(p1, 8);
    if (l == 0) {
        float bb = mw[272];
        out[p]      = p0 + c[a0] + bb;
        out[ET + p] = p1 + c[a1] + bb;
    }
}

extern "C" void kernel_launch(void* const* d_in, const int* in_sizes, int n_in,
                              void* d_out, int out_size, void* d_ws, size_t ws_size,
                              hipStream_t stream) {
    const float* x    = (const float*)d_in[0];
    const int*   tei  = (const int*)d_in[1];
    const int*   tpos = (const int*)d_in[2];
    const int*   tneg = (const int*)d_in[3];
    const float* W1   = (const float*)d_in[4];
    const float* b1   = (const float*)d_in[5];
    const float* W2   = (const float*)d_in[6];
    const float* b2   = (const float*)d_in[7];
    float* out = (float*)d_out;

    int n   = in_sizes[0] / 256;    // 100000 nodes
    int E   = in_sizes[1] / 2;      // 3.2M train edges
    int ET  = in_sizes[2] / 2;      // 500K test edges each
    int nb1 = (n + 511) >> 9;       // 196 coarse buckets

    // workspace layout (no aliasing)
    char* w = (char*)d_ws;
    int*   gtail  = (int*)w;        w += 256 * 4;
    float* mw     = (float*)w;      w += 512 * 4;
    int*   rowptr = (int*)w;        w += (size_t)n * 4;
    int*   counts = (int*)w;        w += (size_t)n * 4;
    float* dinv   = (float*)w;      w += (size_t)n * 4;
    float* hs     = (float*)w;      w += (size_t)16 * n * 4;
    float* gs     = (float*)w;      w += (size_t)16 * n * 4;
    float* u      = (float*)w;      w += (size_t)16 * n * 4;
    float* y      = (float*)w;      w += (size_t)16 * n * 4;
    float* c      = (float*)w;      w += (size_t)n * 4;
    int*   eidx   = (int*)w;        w += (size_t)nb1 * CAP * 4;
    unsigned* tmp = (unsigned*)w;   w += (size_t)nb1 * CAP * 4;

    const int* src = tei;
    const int* dst = tei + E;

    seedprep_kernel<<<1, 256, 0, stream>>>(gtail, nb1, W2, b2, mw);
    passA1_kernel<<<(E + CHUNK - 1) / CHUNK, 256, 0, stream>>>(src, dst, E, gtail, tmp, nb1);
    fill2_kernel<<<nb1, 256, 0, stream>>>(gtail, tmp, eidx, rowptr, counts, dinv, n);

    gemm1_kernel<<<(n + 63) / 64, 64, 0, stream>>>(x, W1, dinv, hs, n);
    agg1_kernel<<<(8 * n + 255) / 256, 256, 0, stream>>>(rowptr, counts, eidx,
                                                         (const float4*)hs, dinv, b1,
                                                         (float4*)gs, n);
    agg2y_kernel<<<(n + 31) / 32, 256, 0, stream>>>(rowptr, counts, eidx,
                                                    (const float4*)gs, dinv, mw,
                                                    (float4*)u, y, c, n);
    edge_dot_kernel<<<(16 * ET + 255) / 256, 256, 0, stream>>>(tpos, tpos + ET, tneg, tneg + ET,
                                                               ET, u, y, c, mw, out);
}